// Round 6
// baseline (18345.734 us; speedup 1.0000x reference)
//
#include <hip/hip_runtime.h>

#define DEV __device__ __forceinline__

constexpr int Bb = 64, Tt = 512, Ii = 256, Hd = 512;
constexpr int NWG = 256, NTHR = 256;

// ---- workspace layout (floats) ----
// uints [0,1024): leaf arrival counters, 32 @ stride 32 uints (128B)
// uint  2048: root counter
// uints [4096,5120): per-leaf gen flags, 32 @ stride 32
// uints [8192, 8192+112*32): counters @ stride 32:
//   PROD_A:0-31 PROD_B:32-47 PROD_C:48-55 PROD_X:56-59 FIN_A:64-95 FIN_B:96-111
constexpr int OFF_G  = 16384;                 // gates σ'd: [4][64][512]
constexpr int OFF_F  = OFF_G + 4 * Bb * Hd;   // F0 = z σ'd; F1 = R·H materialized
constexpr int OFF_HB = OFF_F + 2 * Bb * Hd;   // H double-buffer: [2][64][512]
constexpr int OFF_XB = OFF_HB + 2 * Bb * Hd;  // X-mixed double-buffer: [2][64][256]
constexpr int OFF_PA = OFF_XB + 2 * Bb * Ii;  // A partials: 32 tiles × 8 × 4096
constexpr int OFF_PB = OFF_PA + 32 * 8 * 4096;// B partials: 16 × 16 × 4096
constexpr int OFF_PC = OFF_PB + 16 * 16 * 4096;// C partials: 8 × 8 × 4096
constexpr int OFF_PX = OFF_PC + 8 * 8 * 4096; // X partials: 4 × 8 × 4096

#define SMEM_BYTES (96*36*4 + 96*128*4)       // ldsA[96][36] + ldsW[96][128] = 62976 B

// ---- dependency edges (audit) ----
// Intra-step RAW:  A.finals(G)  -> B.stage (FIN_A[1 tile] >= 8t, per-ks mapping)
//                  A.finals(G1/G3) -> B.r-reduce  (transitively: all 16 B producers of the
//                     r-tile waited FIN_A on G1/G3 Nt 0..3 before PROD_B; tile_wait_B => visible)
//                  B.finals(F1) -> C.stage (FIN_B[r-tiles covering k-range] >= 16t)
//                  B.finals(F0) + A.finals(G0/G2) -> C.epilogue (explicit waits, pre-satisfied)
// Cross-step WAR:  single gbar(t) — every step-t reader of {PA,PB,PC,PX,G,F,HB,XB} arrives at
//                  gbar only after its reads; step-t+1 writers start after gbar. HB/XB parity
//                  gives writers a 2-step distance.

struct P {
  const float *tt, *mark;
  const float *Wxz_t, *Wxr_t, *Wxz_m, *Wxr_m, *Wxh;
  const float *Whz_t, *Whr_t, *Whz_m, *Whr_m, *Whh;
  const float *bz_t, *br_t, *bz_m, *br_m, *bh;
  const float *fWrt, *fWrm, *fWzt, *fWzm, *fWxt, *fWxm;
  const float *frb, *fzb, *fxb;
  float* out; float* ws;
};

enum { JA = 0, JB = 1, JCH = 2, JX = 3 };

DEV float sig1(float x) { return 1.f / (1.f + __expf(-x)); }
DEV float tanh1(float x) { return 2.f * sig1(2.f * x) - 1.f; }
DEV float4 ld4(const float* p) { return *(const float4*)p; }

DEV float2 ld2v(const float* p) {
  unsigned long long u = __hip_atomic_load((const unsigned long long*)p,
                                           __ATOMIC_RELAXED, __HIP_MEMORY_SCOPE_AGENT);
  return __builtin_bit_cast(float2, u);
}
DEV void st2v(float* p, float2 v) {
  __hip_atomic_store((unsigned long long*)p, __builtin_bit_cast(unsigned long long, v),
                     __ATOMIC_RELAXED, __HIP_MEMORY_SCOPE_AGENT);
}
DEV float4 ld4v(const float* p) {
  float2 a = ld2v(p), b = ld2v(p + 2);
  return make_float4(a.x, a.y, b.x, b.y);
}

template<int TYPE>
DEV float4 loadA4(const P& p, int t, const float* aux, int side, int b, int k) {
  const float* ws = p.ws;
  if constexpr (TYPE == JA) {          // [X_raw(256) | H(t-1)(512)]
    if (k < Ii) return ld4(&aux[(b * Tt + (t - 1)) * Ii + k]);
    return ld4v(ws + OFF_HB + ((t - 1) & 1) * Bb * Hd + b * Hd + (k - Ii));
  } else if constexpr (TYPE == JB) {   // [Zt|Zm] (side0) or [Rt|Rm] (side1)
    const int g = (k < Hd) ? side : side + 2;
    const int j = (k < Hd) ? k : k - Hd;
    return ld4v(ws + OFF_G + g * Bb * Hd + b * Hd + j);
  } else if constexpr (TYPE == JCH) {  // [X_mixed(256) | R·H(512)]
    if (k < Ii) return ld4v(ws + OFF_XB + (t & 1) * Bb * Ii + b * Ii + k);
    return ld4v(ws + OFF_F + Bb * Hd + b * Hd + (k - Ii));
  } else {                             // JX: [Xt_raw | Xm_raw], row t
    if (k < Ii) return ld4(&p.tt[(b * Tt + t) * Ii + k]);
    return ld4(&p.mark[(b * Tt + t) * Ii + (k - Ii)]);
  }
}

template<int TYPE, int KC>
DEV void gemm_job(const P& p, float* sm, int t, const float* aux, int side,
                  int brow0, int n0, int K0,
                  const float* wA, int sA, const float* wB, int sB, int kSpl,
                  float* partSlab) {
  float* ldsA = sm;             // [KC][36]
  float* ldsW = sm + 96 * 36;   // [KC][128]
  const int tid = threadIdx.x;
  constexpr int kq = KC >> 2;
  for (int idx = tid; idx < (kq << 5); idx += NTHR) {
    const int m = idx / kq, k4 = idx - m * kq;
    const int k = K0 + (k4 << 2);
    float4 av = loadA4<TYPE>(p, t, aux, side, brow0 + m, k);
    float* d = &ldsA[(k4 << 2) * 36 + m];
    d[0] = av.x; d[36] = av.y; d[72] = av.z; d[108] = av.w;
  }
  for (int idx = tid; idx < (KC << 5); idx += NTHR) {
    const int kk = idx >> 5, nj = (idx & 31) << 2;
    const int k = K0 + kk, n = n0 + nj;
    float4 wv = (k < kSpl) ? ld4(&wA[k * sA + n]) : ld4(&wB[(k - kSpl) * sB + n]);
    *(float4*)&ldsW[(kk << 7) + nj] = wv;
  }
  __syncthreads();
  const int wv_ = tid >> 6, lane = tid & 63, mg = lane >> 4, ng = lane & 15;
  float acc[8][8];
  #pragma unroll
  for (int i = 0; i < 8; ++i)
    #pragma unroll
    for (int j = 0; j < 8; ++j) acc[i][j] = 0.f;
  constexpr int kcw = KC >> 2;
  for (int kk = wv_ * kcw, ke = (wv_ + 1) * kcw; kk < ke; ++kk) {
    float4 a0 = ld4(&ldsA[kk * 36 + (mg << 3)]);
    float4 a1 = ld4(&ldsA[kk * 36 + (mg << 3) + 4]);
    float4 w0 = ld4(&ldsW[(kk << 7) + (ng << 3)]);
    float4 w1 = ld4(&ldsW[(kk << 7) + (ng << 3) + 4]);
    const float am[8] = {a0.x,a0.y,a0.z,a0.w,a1.x,a1.y,a1.z,a1.w};
    const float wn[8] = {w0.x,w0.y,w0.z,w0.w,w1.x,w1.y,w1.z,w1.w};
    #pragma unroll
    for (int mi = 0; mi < 8; ++mi)
      #pragma unroll
      for (int ni = 0; ni < 8; ++ni)
        acc[mi][ni] = fmaf(am[mi], wn[ni], acc[mi][ni]);
  }
  __syncthreads();
  float* red = sm;
  if (wv_ < 2) {
    float* rb = &red[wv_ * 4096];
    #pragma unroll
    for (int mi = 0; mi < 8; ++mi) {
      float* q = &rb[((mg << 3) + mi) * 128 + (ng << 3)];
      *(float4*)q       = make_float4(acc[mi][0], acc[mi][1], acc[mi][2], acc[mi][3]);
      *(float4*)(q + 4) = make_float4(acc[mi][4], acc[mi][5], acc[mi][6], acc[mi][7]);
    }
  }
  __syncthreads();
  if (wv_ >= 2) {
    float* rb = &red[(wv_ - 2) * 4096];
    #pragma unroll
    for (int mi = 0; mi < 8; ++mi) {
      float* q = &rb[((mg << 3) + mi) * 128 + (ng << 3)];
      float4 c0 = ld4(q), c1 = ld4(q + 4);
      *(float4*)q       = make_float4(c0.x+acc[mi][0], c0.y+acc[mi][1], c0.z+acc[mi][2], c0.w+acc[mi][3]);
      *(float4*)(q + 4) = make_float4(c1.x+acc[mi][4], c1.y+acc[mi][5], c1.z+acc[mi][6], c1.w+acc[mi][7]);
    }
  }
  __syncthreads();
  for (int i = tid; i < 2048; i += NTHR) {
    float2 v = make_float2(red[2*i] + red[4096 + 2*i], red[2*i+1] + red[4096 + 2*i+1]);
    st2v(partSlab + 2 * i, v);
  }
}

DEV float2 redsumN(const float* part, int e0, int S) {
  float2 s = make_float2(0.f, 0.f);
  #pragma unroll 4
  for (int q = 0; q < S; ++q) {
    float2 v = ld2v(part + q * 4096 + e0);
    s.x += v.x; s.y += v.y;
  }
  return s;
}

DEV unsigned* ctr(float* ws, int idx) { return (unsigned*)ws + 8192 + idx * 32; }

// producer arrival gate: all S partial slabs of this tile stored (vmcnt-drained)
DEV void tile_wait(float* ws, int tcIdx, unsigned target) {
  __syncthreads();
  if (threadIdx.x == 0) {
    asm volatile("s_waitcnt vmcnt(0)" ::: "memory");
    unsigned* c = ctr(ws, tcIdx);
    __hip_atomic_fetch_add(c, 1u, __ATOMIC_RELAXED, __HIP_MEMORY_SCOPE_AGENT);
    while (__hip_atomic_load(c, __ATOMIC_RELAXED, __HIP_MEMORY_SCOPE_AGENT) < target)
      __builtin_amdgcn_s_sleep(1);
  }
  __syncthreads();
}

// publish: my final slice is stored and drained
DEV void fin_bump(float* ws, int idx) {
  __syncthreads();
  if (threadIdx.x == 0) {
    asm volatile("s_waitcnt vmcnt(0)" ::: "memory");
    __hip_atomic_fetch_add(ctr(ws, idx), 1u, __ATOMIC_RELAXED, __HIP_MEMORY_SCOPE_AGENT);
  }
}

DEV void fin_wait1(float* ws, int idx, unsigned target) {
  if (threadIdx.x == 0) {
    unsigned* c = ctr(ws, idx);
    while (__hip_atomic_load(c, __ATOMIC_RELAXED, __HIP_MEMORY_SCOPE_AGENT) < target)
      __builtin_amdgcn_s_sleep(1);
  }
  __syncthreads();
}

// end-of-step global barrier (decontended tree, unchanged from round 5)
DEV void gbar(float* ws, int wg, unsigned tgt) {
  __syncthreads();
  if (threadIdx.x == 0) {
    asm volatile("s_waitcnt vmcnt(0)" ::: "memory");
    unsigned* base = (unsigned*)ws;
    unsigned* leaf = base + (wg >> 3) * 32;
    unsigned* root = base + 2048;
    unsigned* lgen = base + 4096 + (wg >> 3) * 32;
    unsigned a = __hip_atomic_fetch_add(leaf, 1u, __ATOMIC_RELAXED, __HIP_MEMORY_SCOPE_AGENT);
    if ((a & 7u) == 7u) {
      unsigned r = __hip_atomic_fetch_add(root, 1u, __ATOMIC_RELAXED, __HIP_MEMORY_SCOPE_AGENT);
      if ((r & 31u) == 31u) {
        #pragma unroll 4
        for (int i = 0; i < 32; ++i)
          __hip_atomic_store(base + 4096 + i * 32, tgt, __ATOMIC_RELAXED, __HIP_MEMORY_SCOPE_AGENT);
      }
    }
    while (__hip_atomic_load(lgen, __ATOMIC_RELAXED, __HIP_MEMORY_SCOPE_AGENT) < tgt)
      __builtin_amdgcn_s_sleep(1);
  }
  __syncthreads();
}

__global__ void ggru_init(float* ws) {
  const int i = blockIdx.x * 256 + threadIdx.x;
  if (i < 16384) ws[i] = 0.f;
  const int j = i - 16384;
  if (j >= 0 && j < Bb * Hd) ws[OFF_HB + j] = 0.f;
}

__global__ __launch_bounds__(NTHR)
void ggru_persist(P p) {
  extern __shared__ float sm[];
  const int wg = blockIdx.x, tid = threadIdx.x;
  float* ws = p.ws;

  // ---------- prologue: X-mix for step 1 (input row 0) ----------
  if (wg < 32) {
    const int ks = wg & 7, tile = wg >> 3;
    const int Mt = tile & 1, Nt = tile >> 1, n0 = Nt * 128;
    float* part = ws + OFF_PX + tile * (8 * 4096);
    gemm_job<JX, 64>(p, sm, 0, nullptr, 0, Mt * 32, n0, ks * 64,
                     p.fWxt, Ii, p.fWxm, Ii, Ii, part + ks * 4096);
    tile_wait(ws, 56 + tile, 8u);
    const int e0 = (ks * 256 + tid) * 2;
    float2 s = redsumN(part, e0, 8);
    const int c = e0 & 127, brow = Mt * 32 + (e0 >> 7), col = n0 + c;
    float2 bv = *(const float2*)&p.fxb[col];
    float xg0 = sig1(s.x + bv.x), xg1 = sig1(s.y + bv.y);
    float2 xt = *(const float2*)&p.tt[(brow * Tt + 0) * Ii + col];
    float2 xm = *(const float2*)&p.mark[(brow * Tt + 0) * Ii + col];
    st2v(ws + OFF_XB + 1 * Bb * Ii + brow * Ii + col,
         make_float2(xg0 * xt.x + (1.f - xg0) * xm.x, xg1 * xt.y + (1.f - xg1) * xm.y));
  }
  gbar(ws, wg, 1u);

  for (int t = 1; t <= Tt; ++t) {
    // ---------- phase A: 4 gate pre-acts, σ'd -> G; publish FIN_A ----------
    {
      const int ks = wg & 7, tile = wg >> 3;           // tile = 8*gate + 2*Nt + Mt
      const int Mt = tile & 1, ntl = tile >> 1;
      const int gate = ntl >> 2, Nt = ntl & 3, n0 = Nt * 128;
      const float* wx = gate==0 ? p.Wxz_t : gate==1 ? p.Wxr_t : gate==2 ? p.Wxz_m : p.Wxr_m;
      const float* wh = gate==0 ? p.Whz_t : gate==1 ? p.Whr_t : gate==2 ? p.Whz_m : p.Whr_m;
      const float* xin = (gate < 2) ? p.tt : p.mark;
      float* part = ws + OFF_PA + tile * (8 * 4096);
      gemm_job<JA, 96>(p, sm, t, xin, 0, Mt * 32, n0, ks * 96,
                       wx, Hd, wh, Hd, Ii, part + ks * 4096);
      tile_wait(ws, tile, 8u * (unsigned)t);
      const int e0 = (ks * 256 + tid) * 2;
      float2 s = redsumN(part, e0, 8);
      const int c = e0 & 127, brow = Mt * 32 + (e0 >> 7), col = n0 + c;
      const float* bias = gate==0 ? p.bz_t : gate==1 ? p.br_t : gate==2 ? p.bz_m : p.br_m;
      float2 bv = *(const float2*)&bias[col];
      st2v(ws + OFF_G + gate * Bb * Hd + brow * Hd + col,
           make_float2(sig1(s.x + bv.x), sig1(s.y + bv.y)));
      fin_bump(ws, 64 + tile);
    }
    // ---------- phase B: fused z/r; r-side materializes R·H; publish FIN_B ----------
    {
      const int ks = wg & 15, tile = wg >> 4;          // tile = 8*sd + 2*Nt + Mt
      const int Mt = tile & 1, ntl = tile >> 1;
      const int sd = ntl >> 2, Nt = ntl & 3, n0 = Nt * 128;
      // RAW edge: my k-slab stages exactly one A-tile (Mt, gA, NtA)
      const int gA  = (ks < 8) ? sd : sd + 2;
      const int NtA = (ks < 8) ? (ks >> 1) : ((ks - 8) >> 1);
      fin_wait1(ws, 64 + 8 * gA + 2 * NtA + Mt, 8u * (unsigned)t);
      const float* wa = sd ? p.fWrt : p.fWzt;
      const float* wb = sd ? p.fWrm : p.fWzm;
      float* part = ws + OFF_PB + tile * (16 * 4096);
      gemm_job<JB, 64>(p, sm, t, nullptr, sd, Mt * 32, n0, ks * 64,
                       wa, Hd, wb, Hd, Hd, part + ks * 4096);
      tile_wait(ws, 32 + tile, 16u * (unsigned)t);
      if (tid < 128) {
        const int e0 = (ks * 128 + tid) * 2;
        float2 s = redsumN(part, e0, 16);
        const int c = e0 & 127, brow = Mt * 32 + (e0 >> 7), col = n0 + c;
        const int base = brow * Hd + col;
        const float* bias = sd ? p.frb : p.fzb;
        float2 bv = *(const float2*)&bias[col];
        float2 g = make_float2(sig1(s.x + bv.x), sig1(s.y + bv.y));
        if (sd == 0) {
          st2v(ws + OFF_F + base, g);                  // z
        } else {                                       // R·H (G1/G3 visible via tile_wait_B)
          float2 rt = ld2v(ws + OFF_G + 1 * Bb * Hd + base);
          float2 rm = ld2v(ws + OFF_G + 3 * Bb * Hd + base);
          float2 ho = ld2v(ws + OFF_HB + ((t - 1) & 1) * Bb * Hd + base);
          st2v(ws + OFF_F + Bb * Hd + base,
               make_float2((g.x * rt.x + (1.f - g.x) * rm.x) * ho.x,
                           (g.y * rt.y + (1.f - g.y) * rm.y) * ho.y));
        }
      }
      fin_bump(ws, 96 + tile);
    }
    // ---------- phase C: H̃ GEMM + H(t) + out; X-mix(t+1) ----------
    if (wg < 64) {
      const int ks = wg & 7, tile = wg >> 3;           // 8 tiles × 8 k-slabs
      const int Mt = tile & 1, NtC = tile >> 1, n0 = NtC * 128;
      // RAW edge: F1 (R·H) r-tiles covering my H-col range
      {
        const int lo = ks * 96, hi = lo + 96;
        if (tid == 0 && hi > 256) {
          const int b0 = ((lo > 256 ? lo : 256) - 256) >> 7, b1 = (hi - 1 - 256) >> 7;
          for (int b = b0; b <= b1; ++b) {
            unsigned* c = ctr(ws, 96 + 8 + 2 * b + Mt);
            while (__hip_atomic_load(c, __ATOMIC_RELAXED, __HIP_MEMORY_SCOPE_AGENT) < 16u * (unsigned)t)
              __builtin_amdgcn_s_sleep(1);
          }
        }
        __syncthreads();
      }
      float* part = ws + OFF_PC + tile * (8 * 4096);
      gemm_job<JCH, 96>(p, sm, t, nullptr, 0, Mt * 32, n0, ks * 96,
                        p.Wxh, Hd, p.Whh, Hd, Ii, part + ks * 4096);
      tile_wait(ws, 48 + tile, 8u * (unsigned)t);
      // epilogue RAW edges: z-tile (FIN_B), gate0/gate2 tiles (FIN_A) — typically pre-satisfied
      if (tid == 0) {
        unsigned tgtB = 16u * (unsigned)t, tgtA = 8u * (unsigned)t;
        unsigned* c0 = ctr(ws, 96 + 2 * NtC + Mt);
        while (__hip_atomic_load(c0, __ATOMIC_RELAXED, __HIP_MEMORY_SCOPE_AGENT) < tgtB)
          __builtin_amdgcn_s_sleep(1);
        unsigned* c1 = ctr(ws, 64 + 2 * NtC + Mt);
        while (__hip_atomic_load(c1, __ATOMIC_RELAXED, __HIP_MEMORY_SCOPE_AGENT) < tgtA)
          __builtin_amdgcn_s_sleep(1);
        unsigned* c2 = ctr(ws, 64 + 16 + 2 * NtC + Mt);
        while (__hip_atomic_load(c2, __ATOMIC_RELAXED, __HIP_MEMORY_SCOPE_AGENT) < tgtA)
          __builtin_amdgcn_s_sleep(1);
      }
      __syncthreads();
      const int e0 = (ks * 256 + tid) * 2;
      float2 s = redsumN(part, e0, 8);
      const int c = e0 & 127, brow = Mt * 32 + (e0 >> 7), col = n0 + c;
      float2 bv = *(const float2*)&p.bh[col];
      float ht0 = tanh1(s.x + bv.x), ht1 = tanh1(s.y + bv.y);
      const int base = brow * Hd + col;
      float2 zf = ld2v(ws + OFF_F + base);
      float2 zt = ld2v(ws + OFF_G + base);
      float2 zm = ld2v(ws + OFF_G + 2 * Bb * Hd + base);
      float2 ho = ld2v(ws + OFF_HB + ((t - 1) & 1) * Bb * Hd + base);
      float Z0 = zf.x * zt.x + (1.f - zf.x) * zm.x;
      float Z1 = zf.y * zt.y + (1.f - zf.y) * zm.y;
      float2 hn = make_float2(Z0 * ho.x + (1.f - Z0) * ht0, Z1 * ho.y + (1.f - Z1) * ht1);
      st2v(ws + OFF_HB + (t & 1) * Bb * Hd + base, hn);
      *(float2*)&p.out[(brow * Tt + (t - 1)) * Hd + col] = hn;
      if (t == Tt) *(float2*)&p.out[Bb * Tt * Hd + brow * Hd + col] = hn;
    } else if (wg < 96 && t < Tt) {
      const int w2 = wg - 64;
      const int ks = w2 & 7, tile = w2 >> 3;           // 4 tiles × 8 k-slabs
      const int Mt = tile & 1, Nt = tile >> 1, n0 = Nt * 128;
      float* part = ws + OFF_PX + tile * (8 * 4096);
      gemm_job<JX, 64>(p, sm, t, nullptr, 0, Mt * 32, n0, ks * 64,
                       p.fWxt, Ii, p.fWxm, Ii, Ii, part + ks * 4096);
      tile_wait(ws, 56 + tile, 8u * (unsigned)(t + 1));
      const int e0 = (ks * 256 + tid) * 2;
      float2 s = redsumN(part, e0, 8);
      const int c = e0 & 127, brow = Mt * 32 + (e0 >> 7), col = n0 + c;
      float2 bv = *(const float2*)&p.fxb[col];
      float xg0 = sig1(s.x + bv.x), xg1 = sig1(s.y + bv.y);
      float2 xt = *(const float2*)&p.tt[(brow * Tt + t) * Ii + col];
      float2 xm = *(const float2*)&p.mark[(brow * Tt + t) * Ii + col];
      st2v(ws + OFF_XB + ((t + 1) & 1) * Bb * Ii + brow * Ii + col,
           make_float2(xg0 * xt.x + (1.f - xg0) * xm.x, xg1 * xt.y + (1.f - xg1) * xm.y));
    }
    // single per-step WAR fence
    gbar(ws, wg, (unsigned)(t + 1));
  }
}

extern "C" void kernel_launch(void* const* d_in, const int* in_sizes, int n_in,
                              void* d_out, int out_size, void* d_ws, size_t ws_size,
                              hipStream_t stream) {
  P pr;
  pr.tt    = (const float*)d_in[0];
  pr.mark  = (const float*)d_in[1];
  pr.Wxz_t = (const float*)d_in[2];
  pr.Wxr_t = (const float*)d_in[3];
  pr.Wxz_m = (const float*)d_in[4];
  pr.Wxr_m = (const float*)d_in[5];
  pr.Wxh   = (const float*)d_in[6];
  pr.Whz_t = (const float*)d_in[7];
  pr.Whr_t = (const float*)d_in[8];
  pr.Whz_m = (const float*)d_in[9];
  pr.Whr_m = (const float*)d_in[10];
  pr.Whh   = (const float*)d_in[11];
  pr.bz_t  = (const float*)d_in[12];
  pr.br_t  = (const float*)d_in[13];
  pr.bz_m  = (const float*)d_in[14];
  pr.br_m  = (const float*)d_in[15];
  pr.bh    = (const float*)d_in[16];
  pr.fWrt  = (const float*)d_in[17];
  pr.fWrm  = (const float*)d_in[18];
  pr.fWzt  = (const float*)d_in[19];
  pr.fWzm  = (const float*)d_in[20];
  pr.fWxt  = (const float*)d_in[21];
  pr.fWxm  = (const float*)d_in[22];
  pr.frb   = (const float*)d_in[23];
  pr.fzb   = (const float*)d_in[24];
  pr.fxb   = (const float*)d_in[25];
  pr.out = (float*)d_out;
  pr.ws  = (float*)d_ws;

  hipLaunchKernelGGL(ggru_init, dim3(192), dim3(256), 0, stream, (float*)d_ws);

  void* args[] = { (void*)&pr };
  hipError_t err = hipLaunchCooperativeKernel((const void*)ggru_persist,
                                              dim3(NWG), dim3(NTHR),
                                              args, (unsigned)SMEM_BYTES, stream);
  if (err != hipSuccess) {
    hipLaunchKernelGGL(ggru_persist, dim3(NWG), dim3(NTHR), SMEM_BYTES, stream, pr);
  }
}